// Round 8
// baseline (467.324 us; speedup 1.0000x reference)
//
#include <hip/hip_runtime.h>
#include <cstdint>
#include <cstddef>

typedef unsigned short u16;
typedef short bf16x8 __attribute__((ext_vector_type(8)));
typedef short bf16x4 __attribute__((ext_vector_type(4)));
typedef float f32x4 __attribute__((ext_vector_type(4)));

constexpr int B_ = 4, T_ = 1024, E_ = 1024, H_ = 16, D_ = 64;

__device__ __forceinline__ float bf2f(u16 u) {
  union { unsigned u; float f; } v; v.u = ((unsigned)u) << 16; return v.f;
}
__device__ __forceinline__ u16 f2bf(float f) {
  union { float f; unsigned u; } v; v.f = f;
  return (u16)((v.u + 0x7fffu + ((v.u >> 16) & 1u)) >> 16);
}

#define GLD_LDS16(gp, lp)                                                      \
  __builtin_amdgcn_global_load_lds(                                            \
      (const __attribute__((address_space(1))) void*)(gp),                     \
      (__attribute__((address_space(3))) void*)(lp), 16, 0, 0)

// ---------------------------------------------------------------------------
// GEMM body, C = alpha * A @ B^T. Fragment-major LDS staging:
// slot s = frag*64 + lane holds A(row = frag*16 + (s&15), k-chunk (s>>4)&3).
// MFMA frag reads are lane-contiguous 16B -> bank-conflict-free (round-8 fix;
// old row-major layout had 64B lane stride = 8-way conflicts, 4.19M cyc/disp).
// ---------------------------------------------------------------------------
template<int WM, int WN, int MT, int NT, bool CBF16>
__device__ __forceinline__ void gemm_body(
    u16* smem, int bx, int by, int bz,
    const u16* __restrict__ A, const u16* __restrict__ Bm,
    void* __restrict__ Cv, int N, int K,
    int lda, int ldb, int ldc,
    long batchA, long batchB, long batchC, float alpha)
{
  constexpr int TM = WM * MT * 16;
  constexpr int TN = WN * NT * 16;
  constexpr int THREADS = WM * WN * 64;
  constexpr int ASZ = TM * 32;

  u16* sA = smem;
  u16* sB = smem + ASZ;

  const u16* Ab = A + (size_t)bz * batchA;
  const u16* Bb = Bm + (size_t)bz * batchB;
  const int m0 = by * TM;
  const int n0 = bx * TN;
  const int tid = threadIdx.x;
  const int lane = tid & 63;
  const int wave = tid >> 6;
  const int wm = wave % WM;
  const int wn = wave / WM;

  f32x4 acc[MT][NT];
  #pragma unroll
  for (int i = 0; i < MT; i++)
    #pragma unroll
    for (int j = 0; j < NT; j++) acc[i][j] = f32x4{0.f, 0.f, 0.f, 0.f};

  for (int k0 = 0; k0 < K; k0 += 32) {
    __syncthreads();
    for (int s = tid; s < TM * 4; s += THREADS) {
      const int row = m0 + (s >> 6) * 16 + (s & 15);
      const int ko  = k0 + ((s >> 4) & 3) * 8;
      GLD_LDS16(Ab + (size_t)row * lda + ko, &sA[s * 8]);
    }
    for (int s = tid; s < TN * 4; s += THREADS) {
      int rr = n0 + (s >> 6) * 16 + (s & 15);
      if (rr > N - 1) rr = N - 1;           // clamp; epilogue masks cols >= N
      const int ko = k0 + ((s >> 4) & 3) * 8;
      GLD_LDS16(Bb + (size_t)rr * ldb + ko, &sB[s * 8]);
    }
    __syncthreads();

    bf16x8 av[MT], bv[NT];
    #pragma unroll
    for (int mt = 0; mt < MT; mt++)
      av[mt] = *(const bf16x8*)&sA[((((wm * MT + mt) << 6) | lane)) * 8];
    #pragma unroll
    for (int nt = 0; nt < NT; nt++)
      bv[nt] = *(const bf16x8*)&sB[((((wn * NT + nt) << 6) | lane)) * 8];
    #pragma unroll
    for (int mt = 0; mt < MT; mt++)
      #pragma unroll
      for (int nt = 0; nt < NT; nt++)
        acc[mt][nt] = __builtin_amdgcn_mfma_f32_16x16x32_bf16(av[mt], bv[nt], acc[mt][nt], 0, 0, 0);
  }

  const int er = (lane >> 4) * 4;
  const int ec = lane & 15;
  #pragma unroll
  for (int mt = 0; mt < MT; mt++) {
    #pragma unroll
    for (int nt = 0; nt < NT; nt++) {
      const int row = m0 + (wm * MT + mt) * 16 + er;
      const int col = n0 + (wn * NT + nt) * 16 + ec;
      if (col < N) {
        #pragma unroll
        for (int r2 = 0; r2 < 4; r2++) {
          const float vv = acc[mt][nt][r2] * alpha;
          const size_t ci = (size_t)bz * batchC + (size_t)(row + r2) * ldc + col;
          if constexpr (CBF16) ((u16*)Cv)[ci] = f2bf(vv);
          else                 ((float*)Cv)[ci] = vv;
        }
      }
    }
  }
}

// standalone instance (qkvr projection)
template<int WM, int WN, int MT, int NT, bool CBF16>
__global__ __launch_bounds__(WM * WN * 64) void gemm_bt(
    const u16* __restrict__ A, const u16* __restrict__ Bm,
    void* __restrict__ Cv, int N, int K, int lda, int ldb, int ldc,
    long batchA, long batchB, long batchC, float alpha)
{
  __shared__ u16 smem[(WM * MT + WN * NT) * 16 * 32];
  gemm_body<WM, WN, MT, NT, CBF16>(smem, blockIdx.x, blockIdx.y, blockIdx.z,
                                   A, Bm, Cv, N, K, lda, ldb, ldc,
                                   batchA, batchB, batchC, alpha);
}

// ---------------------------------------------------------------------------
// gemm_echo: split-bf16 GEMM (fp32-class product), 128x64 tile, frag-major
// staging, fused epilogue: echoT (B,E,T) bf16 via LDS transpose + sc (sum of
// squares) via lane-reduced atomicAdd (sc zeroed in cast_all).
// ---------------------------------------------------------------------------
__global__ __launch_bounds__(256) void gemm_echo(
    const u16* __restrict__ A, const u16* __restrict__ Alo,
    const u16* __restrict__ Bm, const u16* __restrict__ Blo,
    u16* __restrict__ echoT, float* __restrict__ sc)
{
  constexpr int ASZ = 128 * 32, BSZ = 64 * 32;
  __shared__ u16 smem[2 * (ASZ + BSZ)];       // 24 KB; epilogue reuses 64*132
  u16* sA  = smem;
  u16* sB  = smem + ASZ;
  u16* sAl = smem + ASZ + BSZ;
  u16* sBl = smem + 2 * ASZ + BSZ;

  const int m0 = blockIdx.y * 128;
  const int n0 = blockIdx.x * 64;
  const int tid = threadIdx.x;
  const int lane = tid & 63;
  const int wave = tid >> 6;
  const int wm = wave % 2;
  const int wn = wave / 2;
  const int fg = lane >> 4;

  f32x4 acc[4][2];
  #pragma unroll
  for (int i = 0; i < 4; i++)
    #pragma unroll
    for (int j = 0; j < 2; j++) acc[i][j] = f32x4{0.f, 0.f, 0.f, 0.f};

  for (int k0 = 0; k0 < E_; k0 += 32) {
    __syncthreads();
    for (int s = tid; s < 512; s += 256) {
      const int row = m0 + (s >> 6) * 16 + (s & 15);
      const int ko  = k0 + ((s >> 4) & 3) * 8;
      const size_t go = (size_t)row * E_ + ko;
      GLD_LDS16(A + go, &sA[s * 8]);
      GLD_LDS16(Alo + go, &sAl[s * 8]);
    }
    for (int s = tid; s < 256; s += 256) {
      const int row = n0 + (s >> 6) * 16 + (s & 15);
      const int ko  = k0 + ((s >> 4) & 3) * 8;
      const size_t go = (size_t)row * E_ + ko;
      GLD_LDS16(Bm + go, &sB[s * 8]);
      GLD_LDS16(Blo + go, &sBl[s * 8]);
    }
    __syncthreads();

    bf16x8 av[4], bv[2], al[4], bl[2];
    #pragma unroll
    for (int mt = 0; mt < 4; mt++) {
      av[mt] = *(const bf16x8*)&sA[(((wm * 4 + mt) << 6) | lane) * 8];
      al[mt] = *(const bf16x8*)&sAl[(((wm * 4 + mt) << 6) | lane) * 8];
    }
    #pragma unroll
    for (int nt = 0; nt < 2; nt++) {
      bv[nt] = *(const bf16x8*)&sB[(((wn * 2 + nt) << 6) | lane) * 8];
      bl[nt] = *(const bf16x8*)&sBl[(((wn * 2 + nt) << 6) | lane) * 8];
    }
    #pragma unroll
    for (int mt = 0; mt < 4; mt++)
      #pragma unroll
      for (int nt = 0; nt < 2; nt++) {
        acc[mt][nt] = __builtin_amdgcn_mfma_f32_16x16x32_bf16(av[mt], bv[nt], acc[mt][nt], 0, 0, 0);
        acc[mt][nt] = __builtin_amdgcn_mfma_f32_16x16x32_bf16(al[mt], bv[nt], acc[mt][nt], 0, 0, 0);
        acc[mt][nt] = __builtin_amdgcn_mfma_f32_16x16x32_bf16(av[mt], bl[nt], acc[mt][nt], 0, 0, 0);
      }
  }

  // ---- fused epilogue ----
  __syncthreads();
  const int b   = m0 >> 10;
  const int t0l = m0 & 1023;
  const int ec  = lane & 15;
  u16* lt = smem;                  // [f][t] tile, pad 132

  #pragma unroll
  for (int mt = 0; mt < 4; mt++) {
    float sq[4] = {0.f, 0.f, 0.f, 0.f};
    #pragma unroll
    for (int nt = 0; nt < 2; nt++) {
      const int cl = (wn * 2 + nt) * 16 + ec;
      #pragma unroll
      for (int r2 = 0; r2 < 4; r2++) {
        const float vv = acc[mt][nt][r2];
        sq[r2] += vv * vv;
        lt[cl * 132 + (wm * 4 + mt) * 16 + fg * 4 + r2] = f2bf(vv);
      }
    }
    #pragma unroll
    for (int m2 = 1; m2 < 16; m2 <<= 1) {
      sq[0] += __shfl_xor(sq[0], m2, 64);
      sq[1] += __shfl_xor(sq[1], m2, 64);
      sq[2] += __shfl_xor(sq[2], m2, 64);
      sq[3] += __shfl_xor(sq[3], m2, 64);
    }
    if (ec == 0) {
      #pragma unroll
      for (int r2 = 0; r2 < 4; r2++)
        atomicAdd(&sc[(size_t)b * T_ + t0l + (wm * 4 + mt) * 16 + fg * 4 + r2], sq[r2]);
    }
  }
  __syncthreads();
  for (int s = tid; s < 64 * 128; s += 256) {
    const int f = s >> 7, t = s & 127;
    echoT[((size_t)b * E_ + n0 + f) * T_ + t0l + t] = lt[f * 132 + t];
  }
}

// ---------------------------------------------------------------------------
// Flash-fused branch 1 body, register-resident (round-6 win). smem = 48 KB.
// ---------------------------------------------------------------------------
__device__ __forceinline__ void flash_body(
    u16* smem, int it, int h, int b,
    const u16* __restrict__ qkvr, const u16* __restrict__ vTb, u16* __restrict__ out1)
{
  u16* sQ = smem;
  u16* sK = smem + 8192;
  u16* sV = smem + 16384;
  const int tid = threadIdx.x, lane = tid & 63, w = tid >> 6;
  const int fr = lane & 15, fg = lane >> 4;

  const u16* Qb = qkvr + ((size_t)(b * T_) + it * 128) * 4096 + h * 64;
  const u16* Kb = qkvr + (size_t)(b * T_) * 4096 + 1024 + h * 64;
  const u16* Vb = vTb + (size_t)(b * H_ + h) * (D_ * T_);

  for (int s = tid; s < 1024; s += 256) {
    const int l = s & 63, g = s >> 6;
    const int row = (g >> 1) * 16 + (l & 15);
    const int c8  = (g & 1) * 4 + (l >> 4);
    GLD_LDS16(Qb + (size_t)row * 4096 + c8 * 8, &sQ[s * 8]);
  }
  __syncthreads();

  bf16x8 bQ[2][2];
  #pragma unroll
  for (int mf = 0; mf < 2; mf++)
    #pragma unroll
    for (int kk = 0; kk < 2; kk++)
      bQ[mf][kk] = *(const bf16x8*)&sQ[((((w * 2 + mf) * 2 + kk) << 6) | lane) * 8];

  f32x4 accO[2][4];
  float mrow[2], lrow[2];
  #pragma unroll
  for (int mf = 0; mf < 2; mf++) {
    mrow[mf] = -3.0e38f; lrow[mf] = 0.f;
    #pragma unroll
    for (int nd = 0; nd < 4; nd++) accO[mf][nd] = f32x4{0.f, 0.f, 0.f, 0.f};
  }

  for (int jt = 0; jt <= it; jt++) {
    __syncthreads();
    for (int s = tid; s < 1024; s += 256) {
      const int l = s & 63, g = s >> 6;
      const int row = (g >> 1) * 16 + (l & 15);
      const int c8  = (g & 1) * 4 + (l >> 4);
      GLD_LDS16(Kb + (size_t)(jt * 128 + row) * 4096 + c8 * 8, &sK[s * 8]);
    }
    for (int s = tid; s < 1024; s += 256) {
      const int jc = s >> 6, d = s & 63;
      GLD_LDS16(Vb + ((size_t)(jt * 16 + jc)) * 512 + d * 8, &sV[s * 8]);
    }
    __syncthreads();

    f32x4 accST[2][8];
    #pragma unroll
    for (int mf = 0; mf < 2; mf++)
      #pragma unroll
      for (int nf = 0; nf < 8; nf++) accST[mf][nf] = f32x4{0.f, 0.f, 0.f, 0.f};
    #pragma unroll
    for (int kk = 0; kk < 2; kk++) {
      #pragma unroll
      for (int nf = 0; nf < 8; nf++) {
        const bf16x8 aK = *(const bf16x8*)&sK[((((nf << 1) | kk) << 6) | lane) * 8];
        accST[0][nf] = __builtin_amdgcn_mfma_f32_16x16x32_bf16(aK, bQ[0][kk], accST[0][nf], 0, 0, 0);
        accST[1][nf] = __builtin_amdgcn_mfma_f32_16x16x32_bf16(aK, bQ[1][kk], accST[1][nf], 0, 0, 0);
      }
    }

    const bool diag = (jt == it);
    bf16x4 pf[2][8];
    #pragma unroll
    for (int mf = 0; mf < 2; mf++) {
      const int iloc = w * 32 + mf * 16 + fr;
      float sv[8][4];
      float rmax = -3.0e38f;
      #pragma unroll
      for (int nf = 0; nf < 8; nf++)
        #pragma unroll
        for (int r = 0; r < 4; r++) {
          float s = accST[mf][nf][r] * 0.125f;
          if (diag && (nf * 16 + fg * 4 + r) > iloc) s = -3.0e38f;
          sv[nf][r] = s;
          rmax = fmaxf(rmax, s);
        }
      rmax = fmaxf(rmax, __shfl_xor(rmax, 16, 64));
      rmax = fmaxf(rmax, __shfl_xor(rmax, 32, 64));
      const float mn = fmaxf(mrow[mf], rmax);
      const float al = __expf(mrow[mf] - mn);
      mrow[mf] = mn;
      float ps = 0.f;
      #pragma unroll
      for (int nf = 0; nf < 8; nf++)
        #pragma unroll
        for (int r = 0; r < 4; r++) {
          const float pv = __expf(sv[nf][r] - mn);
          ps += pv;
          pf[mf][nf][r] = (short)f2bf(pv);
        }
      ps += __shfl_xor(ps, 16, 64);
      ps += __shfl_xor(ps, 32, 64);
      lrow[mf] = lrow[mf] * al + ps;
      #pragma unroll
      for (int r = 0; r < 4; r++) {
        const float alr = __shfl(al, fg * 4 + r, 64);
        #pragma unroll
        for (int nd = 0; nd < 4; nd++) accO[mf][nd][r] *= alr;
      }
    }

    #pragma unroll
    for (int kc = 0; kc < 8; kc++) {
      bf16x8 bV[4];
      #pragma unroll
      for (int nd = 0; nd < 4; nd++) {
        const bf16x4 vv = *(const bf16x4*)&sV[
            (((kc * 2 + (fg >> 1)) * 64 + nd * 16 + fr) * 8) + (fg & 1) * 4];
        bV[nd] = bf16x8{vv[0], vv[1], vv[2], vv[3], 0, 0, 0, 0};
      }
      #pragma unroll
      for (int mf = 0; mf < 2; mf++) {
        const bf16x4 pp = pf[mf][kc];
        const bf16x8 pA = bf16x8{pp[0], pp[1], pp[2], pp[3], 0, 0, 0, 0};
        #pragma unroll
        for (int nd = 0; nd < 4; nd++)
          accO[mf][nd] = __builtin_amdgcn_mfma_f32_16x16x32_bf16(pA, bV[nd], accO[mf][nd], 0, 0, 0);
      }
    }
  }

  u16* op = out1 + ((size_t)(b * T_) + it * 128) * E_ + h * 64;
  #pragma unroll
  for (int mf = 0; mf < 2; mf++) {
    const float li = 1.0f / lrow[mf];
    #pragma unroll
    for (int r = 0; r < 4; r++) {
      const float linv = __shfl(li, fg * 4 + r, 64);
      const int row = w * 32 + mf * 16 + fg * 4 + r;
      #pragma unroll
      for (int nd = 0; nd < 4; nd++)
        op[(size_t)row * E_ + nd * 16 + fr] = f2bf(accO[mf][nd][r] * linv);
    }
  }
}

// ---------------------------------------------------------------------------
// attn_out3: flash1 (512 blocks) + out3 GEMM (512 blocks) in one dispatch.
// ---------------------------------------------------------------------------
__global__ __launch_bounds__(256) void attn_out3(
    const u16* __restrict__ qkvr, const u16* __restrict__ vTb, u16* __restrict__ out1,
    const u16* __restrict__ a3p, const u16* __restrict__ echoT, u16* __restrict__ out3b)
{
  __shared__ u16 smem[24576];   // 48 KB (flash); gemm uses first 12 KB
  const int bid = blockIdx.x;
  if (bid < 512) {
    flash_body(smem, bid & 7, (bid >> 3) & 15, bid >> 7, qkvr, vTb, out1);
  } else {
    const int g = bid - 512;
    gemm_body<2, 2, 4, 2, true>(smem, g & 15, (g >> 4) & 7, g >> 7,
        a3p, echoT, out3b, E_, T_, T_, T_, E_,
        (long)T_ * T_, (long)E_ * T_, (long)T_ * E_, 1.f);
  }
}

// ---------------------------------------------------------------------------
// gemm_wo: out = comb @ wo^T with comb = gate-combine(o1,o2,o3) computed
// during A-staging (regular loads + VALU + ds_write_b128; B stays on GLD).
// 128x64 tile, frag-major, fp32 C.
// ---------------------------------------------------------------------------
__global__ __launch_bounds__(256) void gemm_wo(
    const u16* __restrict__ o1, const u16* __restrict__ o2, const u16* __restrict__ o3,
    const float* __restrict__ gate, const u16* __restrict__ wob, float* __restrict__ out)
{
  __shared__ u16 sA[4096];
  __shared__ u16 sB[2048];
  __shared__ float gw[16][3];

  const int tid = threadIdx.x;
  const int lane = tid & 63;
  const int wave = tid >> 6;
  const int wm = wave % 2;
  const int wn = wave / 2;
  const int m0 = blockIdx.y * 128;
  const int n0 = blockIdx.x * 64;

  if (tid < 16) {
    const float g0 = gate[tid * 3], g1 = gate[tid * 3 + 1], g2 = gate[tid * 3 + 2];
    const float mx = fmaxf(g0, fmaxf(g1, g2));
    const float e0 = __expf(g0 - mx), e1 = __expf(g1 - mx), e2 = __expf(g2 - mx);
    const float inv = 1.0f / (e0 + e1 + e2);
    gw[tid][0] = e0 * inv; gw[tid][1] = e1 * inv; gw[tid][2] = e2 * inv;
  }

  f32x4 acc[4][2];
  #pragma unroll
  for (int i = 0; i < 4; i++)
    #pragma unroll
    for (int j = 0; j < 2; j++) acc[i][j] = f32x4{0.f, 0.f, 0.f, 0.f};

  for (int k0 = 0; k0 < E_; k0 += 32) {
    __syncthreads();
    for (int s = tid; s < 512; s += 256) {
      const int row = m0 + (s >> 6) * 16 + (s & 15);
      const int ko  = k0 + ((s >> 4) & 3) * 8;
      const size_t go = (size_t)row * E_ + ko;
      const int h = ko >> 6;
      const float g0 = gw[h][0], g1 = gw[h][1], g2 = gw[h][2];
      const bf16x8 v1 = *(const bf16x8*)(o1 + go);
      const bf16x8 v2 = *(const bf16x8*)(o2 + go);
      const bf16x8 v3 = *(const bf16x8*)(o3 + go);
      bf16x8 r;
      #pragma unroll
      for (int j = 0; j < 8; j++)
        r[j] = (short)f2bf(g0 * bf2f((u16)v1[j]) + g1 * bf2f((u16)v2[j]) + g2 * bf2f((u16)v3[j]));
      *(bf16x8*)&sA[s * 8] = r;
    }
    for (int s = tid; s < 256; s += 256) {
      const int row = n0 + (s >> 6) * 16 + (s & 15);
      const int ko  = k0 + ((s >> 4) & 3) * 8;
      GLD_LDS16(wob + (size_t)row * E_ + ko, &sB[s * 8]);
    }
    __syncthreads();

    bf16x8 av[4], bv[2];
    #pragma unroll
    for (int mt = 0; mt < 4; mt++)
      av[mt] = *(const bf16x8*)&sA[(((wm * 4 + mt) << 6) | lane) * 8];
    #pragma unroll
    for (int nt = 0; nt < 2; nt++)
      bv[nt] = *(const bf16x8*)&sB[(((wn * 2 + nt) << 6) | lane) * 8];
    #pragma unroll
    for (int mt = 0; mt < 4; mt++)
      #pragma unroll
      for (int nt = 0; nt < 2; nt++)
        acc[mt][nt] = __builtin_amdgcn_mfma_f32_16x16x32_bf16(av[mt], bv[nt], acc[mt][nt], 0, 0, 0);
  }

  const int er = (lane >> 4) * 4;
  const int ec = lane & 15;
  #pragma unroll
  for (int mt = 0; mt < 4; mt++)
    #pragma unroll
    for (int nt = 0; nt < 2; nt++) {
      const int row = m0 + (wm * 4 + mt) * 16 + er;
      const int col = n0 + (wn * 2 + nt) * 16 + ec;
      #pragma unroll
      for (int r2 = 0; r2 < 4; r2++)
        out[(size_t)(row + r2) * E_ + col] = acc[mt][nt][r2];
    }
}

// ---------------------------------------------------------------------------
// cast_all: x split | wq/wk/wv/wvr -> wcat | wo | wj split | sc zero.
// ---------------------------------------------------------------------------
__global__ __launch_bounds__(256) void cast_all(
    const float* __restrict__ x, const float* __restrict__ wq,
    const float* __restrict__ wk, const float* __restrict__ wv,
    const float* __restrict__ wvr, const float* __restrict__ wo,
    const float* __restrict__ wj,
    u16* __restrict__ xb, u16* __restrict__ xlo, u16* __restrict__ wcat,
    u16* __restrict__ wob, u16* __restrict__ wjb, u16* __restrict__ wjlo,
    float* __restrict__ sc) {
  const int bid = blockIdx.x;
  if (bid < 4096) {
    const size_t i = ((size_t)bid * 256 + threadIdx.x) * 4;
    const float4 v = *(const float4*)(x + i);
    ushort4 oh, ol;
    oh.x = f2bf(v.x); ol.x = f2bf(v.x - bf2f(oh.x));
    oh.y = f2bf(v.y); ol.y = f2bf(v.y - bf2f(oh.y));
    oh.z = f2bf(v.z); ol.z = f2bf(v.z - bf2f(oh.z));
    oh.w = f2bf(v.w); ol.w = f2bf(v.w - bf2f(oh.w));
    *(ushort4*)(xb + i) = oh;
    *(ushort4*)(xlo + i) = ol;
  } else if (bid < 8192) {
    const int r = (bid - 4096) >> 10;
    const float* src = (r == 0) ? wq : (r == 1) ? wk : (r == 2) ? wv : wvr;
    const size_t i = ((size_t)((bid - 4096) & 1023) * 256 + threadIdx.x) * 4;
    const float4 v = *(const float4*)(src + i);
    ushort4 o;
    o.x = f2bf(v.x); o.y = f2bf(v.y); o.z = f2bf(v.z); o.w = f2bf(v.w);
    *(ushort4*)(wcat + (size_t)r * (1 << 20) + i) = o;
  } else if (bid < 9216) {
    const size_t i = ((size_t)(bid - 8192) * 256 + threadIdx.x) * 4;
    const float4 v = *(const float4*)(wo + i);
    ushort4 o;
    o.x = f2bf(v.x); o.y = f2bf(v.y); o.z = f2bf(v.z); o.w = f2bf(v.w);
    *(ushort4*)(wob + i) = o;
  } else if (bid < 10240) {
    const size_t i = ((size_t)(bid - 9216) * 256 + threadIdx.x) * 4;
    const float4 v = *(const float4*)(wj + i);
    ushort4 oh, ol;
    oh.x = f2bf(v.x); ol.x = f2bf(v.x - bf2f(oh.x));
    oh.y = f2bf(v.y); ol.y = f2bf(v.y - bf2f(oh.y));
    oh.z = f2bf(v.z); ol.z = f2bf(v.z - bf2f(oh.z));
    oh.w = f2bf(v.w); ol.w = f2bf(v.w - bf2f(oh.w));
    *(ushort4*)(wjb + i) = oh;
    *(ushort4*)(wjlo + i) = ol;
  } else {
    const float4 z = {0.f, 0.f, 0.f, 0.f};
    for (int i = threadIdx.x; i < 1024; i += 256) ((float4*)sc)[i] = z;
  }
}

// ---------------------------------------------------------------------------
// side_kernel: transpose_v (4096 blocks) + s2_direct (512 blocks).
// ---------------------------------------------------------------------------
__global__ __launch_bounds__(256) void side_kernel(
    const u16* __restrict__ qkvr, u16* __restrict__ vTb,
    const u16* __restrict__ xb, const float* __restrict__ wr, float* __restrict__ s2) {
  __shared__ __align__(16) char sbuf[8 * 4 * 33 * 4];   // max(tile 2112B, red 4224B)
  const int bid = blockIdx.x;
  if (bid < 4096) {
    // transpose_v: v view = qkvr cols [2048,3072), row stride 4096
    const int bh = bid & 63, r = bid >> 6;
    const int b = bh >> 4, h = bh & 15;
    const int d0 = (r & 1) * 32, t0 = (r >> 1) * 32;
    u16 (*tile)[33] = (u16(*)[33])sbuf;
    const int c = threadIdx.x & 31, r0 = threadIdx.x >> 5;
    const u16* v = qkvr + 2048;
    #pragma unroll
    for (int rr = 0; rr < 32; rr += 8) {
      const int t = t0 + rr + r0;
      tile[rr + r0][c] = v[((size_t)b * T_ + t) * 4096 + h * 64 + d0 + c];
    }
    __syncthreads();
    #pragma unroll
    for (int rr = 0; rr < 32; rr += 8) {
      const int d = d0 + rr + r0;
      const int t = t0 + c;
      vTb[((size_t)(bh * 128 + (t >> 3)) * 64 + d) * 8 + (t & 7)] = tile[c][rr + r0];
    }
  } else {
    const int sid = bid - 4096;
    const int t0 = (sid & 31) * 32, h = sid >> 5;
    const int tt = threadIdx.x & 31, eg = threadIdx.x >> 5;
    float acc[4] = {0.f, 0.f, 0.f, 0.f};
    const float* wp = wr + (size_t)h * E_ * T_ + t0 + tt;
    for (int ec = 0; ec < 8; ec++) {
      const int e0 = ec * 128 + eg * 16;
      bf16x8 xv[4][2];
      #pragma unroll
      for (int b = 0; b < 4; b++) {
        const u16* xp = xb + ((size_t)(b * T_) + t0 + tt) * E_ + e0;
        xv[b][0] = *(const bf16x8*)xp;
        xv[b][1] = *(const bf16x8*)(xp + 8);
      }
      #pragma unroll
      for (int e2 = 0; e2 < 16; e2++) {
        const float w = wp[(size_t)(e0 + e2) * T_];
        #pragma unroll
        for (int b = 0; b < 4; b++)
          acc[b] += bf2f((u16)xv[b][e2 >> 3][e2 & 7]) * w;
      }
    }
    float (*red)[4][33] = (float(*)[4][33])sbuf;
    #pragma unroll
    for (int b = 0; b < 4; b++) red[eg][b][tt] = acc[b];
    __syncthreads();
    if (threadIdx.x < 128) {
      const int b = threadIdx.x >> 5, t = threadIdx.x & 31;
      float s = 0.f;
      #pragma unroll
      for (int g = 0; g < 8; g++) s += red[g][b][t];
      s2[((size_t)b * H_ + h) * T_ + t0 + t] = s * 0.125f;
    }
  }
}

// ---------------------------------------------------------------------------
// scan_a3: branch2 prefix scan (64 blocks) + a3 softmax (4096 blocks), 1024 thr.
// ---------------------------------------------------------------------------
__global__ __launch_bounds__(1024) void scan_a3(
    const float* __restrict__ s2, const u16* __restrict__ rv, u16* __restrict__ out2,
    const float* __restrict__ sc, u16* __restrict__ a3p) {
  __shared__ float wbuf[1024];
  __shared__ float numtot[16][64];
  __shared__ float dentot[16];
  __shared__ float redm[16];
  const int bid = blockIdx.x;
  const int tid = threadIdx.x, lane = tid & 63, wv = tid >> 6;

  if (bid < 64) {
    const int h = bid & 15, b = bid >> 4;
    const float* srow = s2 + ((size_t)b * H_ + h) * T_;

    float m = srow[tid];
    #pragma unroll
    for (int mk = 32; mk > 0; mk >>= 1) m = fmaxf(m, __shfl_xor(m, mk, 64));
    if (lane == 0) redm[wv] = m;
    __syncthreads();
    m = redm[0];
    #pragma unroll
    for (int i2 = 1; i2 < 16; i2++) m = fmaxf(m, redm[i2]);

    wbuf[tid] = __expf(srow[tid] - m);
    __syncthreads();

    const u16* rvp = rv + (size_t)(b * T_) * 4096 + h * D_ + lane;
    const int j0 = wv * 64;
    float num = 0.f, den = 0.f;
    #pragma unroll 8
    for (int j2 = 0; j2 < 64; j2++) {
      const float w = wbuf[j0 + j2];
      den += w;
      num += w * bf2f(rvp[(size_t)(j0 + j2) * 4096]);
    }
    numtot[wv][lane] = num;
    if (lane == 0) dentot[wv] = den;
    __syncthreads();

    float num_off = 0.f, den_off = 0.f;
    for (int w2 = 0; w2 < wv; w2++) {
      num_off += numtot[w2][lane];
      den_off += dentot[w2];
    }

    u16* op = out2 + (size_t)b * T_ * E_ + h * D_ + lane;
    num = num_off; den = den_off;
    #pragma unroll 8
    for (int j2 = 0; j2 < 64; j2++) {
      const float w = wbuf[j0 + j2];
      num += w * bf2f(rvp[(size_t)(j0 + j2) * 4096]);
      den += w;
      op[(size_t)(j0 + j2) * E_] = f2bf(num / den);
    }
  } else {
    const int sid = bid - 64;
    const int i = sid & 1023, b = sid >> 10;
    const float* sr = sc + (size_t)b * T_;
    const float sci = sr[i] * 0.03125f;
    const int j = tid;
    const float xv = (j <= i) ? sci * (sr[j] * 0.03125f) : -3.0e38f;
    float m = xv;
    #pragma unroll
    for (int mk = 32; mk > 0; mk >>= 1) m = fmaxf(m, __shfl_xor(m, mk, 64));
    if (lane == 0) redm[wv] = m;
    __syncthreads();
    m = redm[0];
    #pragma unroll
    for (int i2 = 1; i2 < 16; i2++) m = fmaxf(m, redm[i2]);
    const float pv = (j <= i) ? __expf(xv - m) : 0.f;
    float s = pv;
    #pragma unroll
    for (int mk = 32; mk > 0; mk >>= 1) s += __shfl_xor(s, mk, 64);
    __syncthreads();
    if (lane == 0) redm[wv] = s;
    __syncthreads();
    s = 0.f;
    #pragma unroll
    for (int i2 = 0; i2 < 16; i2++) s += redm[i2];
    a3p[((size_t)b * T_ + i) * T_ + j] = f2bf(pv / s);
  }
}

// ---------------------------------------------------------------------------
extern "C" void kernel_launch(void* const* d_in, const int* in_sizes, int n_in,
                              void* d_out, int out_size, void* d_ws, size_t ws_size,
                              hipStream_t stream) {
  (void)in_sizes; (void)n_in; (void)out_size; (void)ws_size;
  const float* x    = (const float*)d_in[0];
  const float* wq   = (const float*)d_in[1];
  const float* wk   = (const float*)d_in[2];
  const float* wv   = (const float*)d_in[3];
  const float* wvr  = (const float*)d_in[4];
  const float* wr   = (const float*)d_in[5];
  const float* wj   = (const float*)d_in[6];
  const float* gate = (const float*)d_in[7];
  const float* wo   = (const float*)d_in[8];
  float* out = (float*)d_out;

  char* p = (char*)d_ws;
  auto alloc = [&](size_t bytes) -> char* {
    char* r = p; p += (bytes + 255) & ~(size_t)255; return r;
  };
  const size_t NTE = (size_t)B_ * T_ * E_;
  const size_t NW  = (size_t)E_ * E_;

  u16* xb    = (u16*)alloc(NTE * 2);
  u16* xlo   = (u16*)alloc(NTE * 2);
  u16* wcat  = (u16*)alloc(4 * NW * 2);
  u16* wjb   = (u16*)alloc(NW * 2);
  u16* wjlo  = (u16*)alloc(NW * 2);
  u16* wob   = (u16*)alloc(NW * 2);
  u16* qkvr  = (u16*)alloc(NTE * 4 * 2);     // (B*T, 4096): q|k|v|rv
  u16* vT    = (u16*)alloc(NTE * 2);         // blocked (bh, t8, d, 8)
  u16* echoT = (u16*)alloc(NTE * 2);         // (B, E, T) bf16
  u16* a3p   = (u16*)alloc(NTE * 2);
  float* sc  = (float*)alloc((size_t)B_ * T_ * 4);
  float* s2  = (float*)alloc((size_t)B_ * H_ * T_ * 4);
  u16* out1b = (u16*)alloc(NTE * 2);
  u16* out2b = (u16*)alloc(NTE * 2);
  u16* out3b = (u16*)alloc(NTE * 2);

  // 1. casts + sc zero
  cast_all<<<dim3(10241), 256, 0, stream>>>(x, wq, wk, wv, wvr, wo, wj,
                                            xb, xlo, wcat, wob, wjb, wjlo, sc);
  // 2. fused q|k|v|rv projection
  gemm_bt<2,2,4,4,true><<<dim3(32, 32, 1), 256, 0, stream>>>(
      xb, wcat, qkvr, 4096, E_, E_, E_, 4096, 0L, 0L, 0L, 1.f);
  // 3. echo split-GEMM (echoT + sc fused epilogue)
  gemm_echo<<<dim3(16, 32, 1), 256, 0, stream>>>(xb, xlo, wjb, wjlo, echoT, sc);
  // 4. transpose_v + s2_direct
  side_kernel<<<dim3(4608), 256, 0, stream>>>(qkvr, vT, xb, wr, s2);
  // 5. branch2 scan + a3 softmax
  scan_a3<<<dim3(4160), 1024, 0, stream>>>(s2, qkvr + 3072, out2b, sc, a3p);
  // 6. flash attention + out3 GEMM
  attn_out3<<<dim3(1024), 256, 0, stream>>>(qkvr, vT, out1b, a3p, echoT, out3b);
  // 7. gated combine fused into wo GEMM
  gemm_wo<<<dim3(16, 32), 256, 0, stream>>>(out1b, out2b, out3b, gate, wob, out);
}

// Round 9
// 415.859 us; speedup vs baseline: 1.1238x; 1.1238x over previous
//
#include <hip/hip_runtime.h>
#include <cstdint>
#include <cstddef>

typedef unsigned short u16;
typedef short bf16x8 __attribute__((ext_vector_type(8)));
typedef short bf16x4 __attribute__((ext_vector_type(4)));
typedef float f32x4 __attribute__((ext_vector_type(4)));

constexpr int B_ = 4, T_ = 1024, E_ = 1024, H_ = 16, D_ = 64;

__device__ __forceinline__ float bf2f(u16 u) {
  union { unsigned u; float f; } v; v.u = ((unsigned)u) << 16; return v.f;
}
__device__ __forceinline__ u16 f2bf(float f) {
  union { float f; unsigned u; } v; v.f = f;
  return (u16)((v.u + 0x7fffu + ((v.u >> 16) & 1u)) >> 16);
}

#define GLD_LDS16(gp, lp)                                                      \
  __builtin_amdgcn_global_load_lds(                                            \
      (const __attribute__((address_space(1))) void*)(gp),                     \
      (__attribute__((address_space(3))) void*)(lp), 16, 0, 0)

// ---------------------------------------------------------------------------
// GEMM body, C = alpha * A @ B^T. ROW-MAJOR staging (round-9 revert):
// lane order ascending in address (64B runs/row) -> TA coalescer-friendly.
// The 8-way frag-read bank conflict this implies costs ~7 us/dispatch;
// frag-major staging (round 8) killed conflicts but fragmented global
// coalescing: 62 -> 84 us. Sorted staging wins. DO NOT re-interleave.
// ---------------------------------------------------------------------------
template<int WM, int WN, int MT, int NT, bool CBF16>
__device__ __forceinline__ void gemm_body(
    u16* smem, int bx, int by, int bz,
    const u16* __restrict__ A, const u16* __restrict__ Bm,
    void* __restrict__ Cv, int N, int K,
    int lda, int ldb, int ldc,
    long batchA, long batchB, long batchC, float alpha)
{
  constexpr int TM = WM * MT * 16;
  constexpr int TN = WN * NT * 16;
  constexpr int THREADS = WM * WN * 64;
  constexpr int ASZ = TM * 32;

  u16* sA = smem;
  u16* sB = smem + ASZ;

  const u16* Ab = A + (size_t)bz * batchA;
  const u16* Bb = Bm + (size_t)bz * batchB;
  const int m0 = by * TM;
  const int n0 = bx * TN;
  const int tid = threadIdx.x;
  const int lane = tid & 63;
  const int wave = tid >> 6;
  const int wm = wave % WM;
  const int wn = wave / WM;
  const int fr = lane & 15;
  const int fg = lane >> 4;

  f32x4 acc[MT][NT];
  #pragma unroll
  for (int i = 0; i < MT; i++)
    #pragma unroll
    for (int j = 0; j < NT; j++) acc[i][j] = f32x4{0.f, 0.f, 0.f, 0.f};

  for (int k0 = 0; k0 < K; k0 += 32) {
    __syncthreads();
    for (int s = tid; s < TM * 4; s += THREADS) {
      const int row = s >> 2, ch = s & 3;
      GLD_LDS16(Ab + (size_t)(m0 + row) * lda + k0 + ch * 8, &sA[s * 8]);
    }
    for (int s = tid; s < TN * 4; s += THREADS) {
      const int row = s >> 2, ch = s & 3;
      int rr = n0 + row; if (rr > N - 1) rr = N - 1;   // clamp; epilogue masks
      GLD_LDS16(Bb + (size_t)rr * ldb + k0 + ch * 8, &sB[s * 8]);
    }
    __syncthreads();

    bf16x8 av[MT], bv[NT];
    #pragma unroll
    for (int mt = 0; mt < MT; mt++)
      av[mt] = *(const bf16x8*)&sA[((wm * MT + mt) * 16 + fr) * 32 + fg * 8];
    #pragma unroll
    for (int nt = 0; nt < NT; nt++)
      bv[nt] = *(const bf16x8*)&sB[((wn * NT + nt) * 16 + fr) * 32 + fg * 8];
    #pragma unroll
    for (int mt = 0; mt < MT; mt++)
      #pragma unroll
      for (int nt = 0; nt < NT; nt++)
        acc[mt][nt] = __builtin_amdgcn_mfma_f32_16x16x32_bf16(av[mt], bv[nt], acc[mt][nt], 0, 0, 0);
  }

  const int er = (lane >> 4) * 4;
  const int ec = lane & 15;
  #pragma unroll
  for (int mt = 0; mt < MT; mt++) {
    #pragma unroll
    for (int nt = 0; nt < NT; nt++) {
      const int row = m0 + (wm * MT + mt) * 16 + er;
      const int col = n0 + (wn * NT + nt) * 16 + ec;
      if (col < N) {
        #pragma unroll
        for (int r2 = 0; r2 < 4; r2++) {
          const float vv = acc[mt][nt][r2] * alpha;
          const size_t ci = (size_t)bz * batchC + (size_t)(row + r2) * ldc + col;
          if constexpr (CBF16) ((u16*)Cv)[ci] = f2bf(vv);
          else                 ((float*)Cv)[ci] = vv;
        }
      }
    }
  }
}

// standalone instance (qkvr projection)
template<int WM, int WN, int MT, int NT, bool CBF16>
__global__ __launch_bounds__(WM * WN * 64) void gemm_bt(
    const u16* __restrict__ A, const u16* __restrict__ Bm,
    void* __restrict__ Cv, int N, int K, int lda, int ldb, int ldc,
    long batchA, long batchB, long batchC, float alpha)
{
  __shared__ u16 smem[(WM * MT + WN * NT) * 16 * 32];
  gemm_body<WM, WN, MT, NT, CBF16>(smem, blockIdx.x, blockIdx.y, blockIdx.z,
                                   A, Bm, Cv, N, K, lda, ldb, ldc,
                                   batchA, batchB, batchC, alpha);
}

// ---------------------------------------------------------------------------
// gemm_echo: split-bf16 GEMM (fp32-class product), 128x64 tile, row-major
// staging, fused epilogue: echoT (B,E,T) bf16 via LDS transpose + sc (sum of
// squares) via lane-reduced atomicAdd (sc zeroed in cast_all).
// ---------------------------------------------------------------------------
__global__ __launch_bounds__(256) void gemm_echo(
    const u16* __restrict__ A, const u16* __restrict__ Alo,
    const u16* __restrict__ Bm, const u16* __restrict__ Blo,
    u16* __restrict__ echoT, float* __restrict__ sc)
{
  constexpr int ASZ = 128 * 32, BSZ = 64 * 32;
  __shared__ u16 smem[2 * (ASZ + BSZ)];       // 24 KB; epilogue reuses 64*132
  u16* sA  = smem;
  u16* sB  = smem + ASZ;
  u16* sAl = smem + ASZ + BSZ;
  u16* sBl = smem + 2 * ASZ + BSZ;

  const int m0 = blockIdx.y * 128;
  const int n0 = blockIdx.x * 64;
  const int tid = threadIdx.x;
  const int lane = tid & 63;
  const int wave = tid >> 6;
  const int wm = wave % 2;
  const int wn = wave / 2;
  const int fr = lane & 15, fg = lane >> 4;

  f32x4 acc[4][2];
  #pragma unroll
  for (int i = 0; i < 4; i++)
    #pragma unroll
    for (int j = 0; j < 2; j++) acc[i][j] = f32x4{0.f, 0.f, 0.f, 0.f};

  for (int k0 = 0; k0 < E_; k0 += 32) {
    __syncthreads();
    for (int s = tid; s < 512; s += 256) {
      const int row = s >> 2, ch = s & 3;
      const size_t go = (size_t)(m0 + row) * E_ + k0 + ch * 8;
      GLD_LDS16(A + go, &sA[s * 8]);
      GLD_LDS16(Alo + go, &sAl[s * 8]);
    }
    for (int s = tid; s < 256; s += 256) {
      const int row = s >> 2, ch = s & 3;
      const size_t go = (size_t)(n0 + row) * E_ + k0 + ch * 8;
      GLD_LDS16(Bm + go, &sB[s * 8]);
      GLD_LDS16(Blo + go, &sBl[s * 8]);
    }
    __syncthreads();

    bf16x8 av[4], bv[2], al[4], bl[2];
    #pragma unroll
    for (int mt = 0; mt < 4; mt++) {
      av[mt] = *(const bf16x8*)&sA[((wm * 4 + mt) * 16 + fr) * 32 + fg * 8];
      al[mt] = *(const bf16x8*)&sAl[((wm * 4 + mt) * 16 + fr) * 32 + fg * 8];
    }
    #pragma unroll
    for (int nt = 0; nt < 2; nt++) {
      bv[nt] = *(const bf16x8*)&sB[((wn * 2 + nt) * 16 + fr) * 32 + fg * 8];
      bl[nt] = *(const bf16x8*)&sBl[((wn * 2 + nt) * 16 + fr) * 32 + fg * 8];
    }
    #pragma unroll
    for (int mt = 0; mt < 4; mt++)
      #pragma unroll
      for (int nt = 0; nt < 2; nt++) {
        acc[mt][nt] = __builtin_amdgcn_mfma_f32_16x16x32_bf16(av[mt], bv[nt], acc[mt][nt], 0, 0, 0);
        acc[mt][nt] = __builtin_amdgcn_mfma_f32_16x16x32_bf16(al[mt], bv[nt], acc[mt][nt], 0, 0, 0);
        acc[mt][nt] = __builtin_amdgcn_mfma_f32_16x16x32_bf16(av[mt], bl[nt], acc[mt][nt], 0, 0, 0);
      }
  }

  // ---- fused epilogue ----
  __syncthreads();
  const int b   = m0 >> 10;
  const int t0l = m0 & 1023;
  const int ec  = lane & 15;
  u16* lt = smem;                  // [f][t] tile, pad 132

  #pragma unroll
  for (int mt = 0; mt < 4; mt++) {
    float sq[4] = {0.f, 0.f, 0.f, 0.f};
    #pragma unroll
    for (int nt = 0; nt < 2; nt++) {
      const int cl = (wn * 2 + nt) * 16 + ec;
      #pragma unroll
      for (int r2 = 0; r2 < 4; r2++) {
        const float vv = acc[mt][nt][r2];
        sq[r2] += vv * vv;
        lt[cl * 132 + (wm * 4 + mt) * 16 + fg * 4 + r2] = f2bf(vv);
      }
    }
    #pragma unroll
    for (int m2 = 1; m2 < 16; m2 <<= 1) {
      sq[0] += __shfl_xor(sq[0], m2, 64);
      sq[1] += __shfl_xor(sq[1], m2, 64);
      sq[2] += __shfl_xor(sq[2], m2, 64);
      sq[3] += __shfl_xor(sq[3], m2, 64);
    }
    if (ec == 0) {
      #pragma unroll
      for (int r2 = 0; r2 < 4; r2++)
        atomicAdd(&sc[(size_t)b * T_ + t0l + (wm * 4 + mt) * 16 + fg * 4 + r2], sq[r2]);
    }
  }
  __syncthreads();
  for (int s = tid; s < 64 * 128; s += 256) {
    const int f = s >> 7, t = s & 127;
    echoT[((size_t)b * E_ + n0 + f) * T_ + t0l + t] = lt[f * 132 + t];
  }
}

// ---------------------------------------------------------------------------
// Flash-fused branch 1 body, register-resident (round-6 win). smem = 48 KB.
// ---------------------------------------------------------------------------
__device__ __forceinline__ void flash_body(
    u16* smem, int it, int h, int b,
    const u16* __restrict__ qkvr, const u16* __restrict__ vTb, u16* __restrict__ out1)
{
  u16* sQ = smem;
  u16* sK = smem + 8192;
  u16* sV = smem + 16384;
  const int tid = threadIdx.x, lane = tid & 63, w = tid >> 6;
  const int fr = lane & 15, fg = lane >> 4;

  const u16* Qb = qkvr + ((size_t)(b * T_) + it * 128) * 4096 + h * 64;
  const u16* Kb = qkvr + (size_t)(b * T_) * 4096 + 1024 + h * 64;
  const u16* Vb = vTb + (size_t)(b * H_ + h) * (D_ * T_);

  for (int s = tid; s < 1024; s += 256) {
    const int l = s & 63, g = s >> 6;
    const int row = (g >> 1) * 16 + (l & 15);
    const int c8  = (g & 1) * 4 + (l >> 4);
    GLD_LDS16(Qb + (size_t)row * 4096 + c8 * 8, &sQ[s * 8]);
  }
  __syncthreads();

  bf16x8 bQ[2][2];
  #pragma unroll
  for (int mf = 0; mf < 2; mf++)
    #pragma unroll
    for (int kk = 0; kk < 2; kk++)
      bQ[mf][kk] = *(const bf16x8*)&sQ[((((w * 2 + mf) * 2 + kk) << 6) | lane) * 8];

  f32x4 accO[2][4];
  float mrow[2], lrow[2];
  #pragma unroll
  for (int mf = 0; mf < 2; mf++) {
    mrow[mf] = -3.0e38f; lrow[mf] = 0.f;
    #pragma unroll
    for (int nd = 0; nd < 4; nd++) accO[mf][nd] = f32x4{0.f, 0.f, 0.f, 0.f};
  }

  for (int jt = 0; jt <= it; jt++) {
    __syncthreads();
    for (int s = tid; s < 1024; s += 256) {
      const int l = s & 63, g = s >> 6;
      const int row = (g >> 1) * 16 + (l & 15);
      const int c8  = (g & 1) * 4 + (l >> 4);
      GLD_LDS16(Kb + (size_t)(jt * 128 + row) * 4096 + c8 * 8, &sK[s * 8]);
    }
    for (int s = tid; s < 1024; s += 256) {
      const int jc = s >> 6, d = s & 63;
      GLD_LDS16(Vb + ((size_t)(jt * 16 + jc)) * 512 + d * 8, &sV[s * 8]);
    }
    __syncthreads();

    f32x4 accST[2][8];
    #pragma unroll
    for (int mf = 0; mf < 2; mf++)
      #pragma unroll
      for (int nf = 0; nf < 8; nf++) accST[mf][nf] = f32x4{0.f, 0.f, 0.f, 0.f};
    #pragma unroll
    for (int kk = 0; kk < 2; kk++) {
      #pragma unroll
      for (int nf = 0; nf < 8; nf++) {
        const bf16x8 aK = *(const bf16x8*)&sK[((((nf << 1) | kk) << 6) | lane) * 8];
        accST[0][nf] = __builtin_amdgcn_mfma_f32_16x16x32_bf16(aK, bQ[0][kk], accST[0][nf], 0, 0, 0);
        accST[1][nf] = __builtin_amdgcn_mfma_f32_16x16x32_bf16(aK, bQ[1][kk], accST[1][nf], 0, 0, 0);
      }
    }

    const bool diag = (jt == it);
    bf16x4 pf[2][8];
    #pragma unroll
    for (int mf = 0; mf < 2; mf++) {
      const int iloc = w * 32 + mf * 16 + fr;
      float sv[8][4];
      float rmax = -3.0e38f;
      #pragma unroll
      for (int nf = 0; nf < 8; nf++)
        #pragma unroll
        for (int r = 0; r < 4; r++) {
          float s = accST[mf][nf][r] * 0.125f;
          if (diag && (nf * 16 + fg * 4 + r) > iloc) s = -3.0e38f;
          sv[nf][r] = s;
          rmax = fmaxf(rmax, s);
        }
      rmax = fmaxf(rmax, __shfl_xor(rmax, 16, 64));
      rmax = fmaxf(rmax, __shfl_xor(rmax, 32, 64));
      const float mn = fmaxf(mrow[mf], rmax);
      const float al = __expf(mrow[mf] - mn);
      mrow[mf] = mn;
      float ps = 0.f;
      #pragma unroll
      for (int nf = 0; nf < 8; nf++)
        #pragma unroll
        for (int r = 0; r < 4; r++) {
          const float pv = __expf(sv[nf][r] - mn);
          ps += pv;
          pf[mf][nf][r] = (short)f2bf(pv);
        }
      ps += __shfl_xor(ps, 16, 64);
      ps += __shfl_xor(ps, 32, 64);
      lrow[mf] = lrow[mf] * al + ps;
      #pragma unroll
      for (int r = 0; r < 4; r++) {
        const float alr = __shfl(al, fg * 4 + r, 64);
        #pragma unroll
        for (int nd = 0; nd < 4; nd++) accO[mf][nd][r] *= alr;
      }
    }

    #pragma unroll
    for (int kc = 0; kc < 8; kc++) {
      bf16x8 bV[4];
      #pragma unroll
      for (int nd = 0; nd < 4; nd++) {
        const bf16x4 vv = *(const bf16x4*)&sV[
            (((kc * 2 + (fg >> 1)) * 64 + nd * 16 + fr) * 8) + (fg & 1) * 4];
        bV[nd] = bf16x8{vv[0], vv[1], vv[2], vv[3], 0, 0, 0, 0};
      }
      #pragma unroll
      for (int mf = 0; mf < 2; mf++) {
        const bf16x4 pp = pf[mf][kc];
        const bf16x8 pA = bf16x8{pp[0], pp[1], pp[2], pp[3], 0, 0, 0, 0};
        #pragma unroll
        for (int nd = 0; nd < 4; nd++)
          accO[mf][nd] = __builtin_amdgcn_mfma_f32_16x16x32_bf16(pA, bV[nd], accO[mf][nd], 0, 0, 0);
      }
    }
  }

  u16* op = out1 + ((size_t)(b * T_) + it * 128) * E_ + h * 64;
  #pragma unroll
  for (int mf = 0; mf < 2; mf++) {
    const float li = 1.0f / lrow[mf];
    #pragma unroll
    for (int r = 0; r < 4; r++) {
      const float linv = __shfl(li, fg * 4 + r, 64);
      const int row = w * 32 + mf * 16 + fg * 4 + r;
      #pragma unroll
      for (int nd = 0; nd < 4; nd++)
        op[(size_t)row * E_ + nd * 16 + fr] = f2bf(accO[mf][nd][r] * linv);
    }
  }
}

// ---------------------------------------------------------------------------
// attn_out3: flash1 (512 blocks) + out3 GEMM (512 blocks) in one dispatch.
// ---------------------------------------------------------------------------
__global__ __launch_bounds__(256) void attn_out3(
    const u16* __restrict__ qkvr, const u16* __restrict__ vTb, u16* __restrict__ out1,
    const u16* __restrict__ a3p, const u16* __restrict__ echoT, u16* __restrict__ out3b)
{
  __shared__ u16 smem[24576];   // 48 KB (flash); gemm uses first 12 KB
  const int bid = blockIdx.x;
  if (bid < 512) {
    flash_body(smem, bid & 7, (bid >> 3) & 15, bid >> 7, qkvr, vTb, out1);
  } else {
    const int g = bid - 512;
    gemm_body<2, 2, 4, 2, true>(smem, g & 15, (g >> 4) & 7, g >> 7,
        a3p, echoT, out3b, E_, T_, T_, T_, E_,
        (long)T_ * T_, (long)E_ * T_, (long)T_ * E_, 1.f);
  }
}

// ---------------------------------------------------------------------------
// gemm_wo: out = comb @ wo^T with comb = gate-combine(o1,o2,o3) computed
// during A-staging (regular loads + VALU + ds_write_b128; B stays on GLD).
// 128x64 tile, row-major staging, fp32 C.
// ---------------------------------------------------------------------------
__global__ __launch_bounds__(256) void gemm_wo(
    const u16* __restrict__ o1, const u16* __restrict__ o2, const u16* __restrict__ o3,
    const float* __restrict__ gate, const u16* __restrict__ wob, float* __restrict__ out)
{
  __shared__ u16 sA[4096];
  __shared__ u16 sB[2048];
  __shared__ float gw[16][3];

  const int tid = threadIdx.x;
  const int lane = tid & 63;
  const int wave = tid >> 6;
  const int wm = wave % 2;
  const int wn = wave / 2;
  const int fr = lane & 15, fg = lane >> 4;
  const int m0 = blockIdx.y * 128;
  const int n0 = blockIdx.x * 64;

  if (tid < 16) {
    const float g0 = gate[tid * 3], g1 = gate[tid * 3 + 1], g2 = gate[tid * 3 + 2];
    const float mx = fmaxf(g0, fmaxf(g1, g2));
    const float e0 = __expf(g0 - mx), e1 = __expf(g1 - mx), e2 = __expf(g2 - mx);
    const float inv = 1.0f / (e0 + e1 + e2);
    gw[tid][0] = e0 * inv; gw[tid][1] = e1 * inv; gw[tid][2] = e2 * inv;
  }

  f32x4 acc[4][2];
  #pragma unroll
  for (int i = 0; i < 4; i++)
    #pragma unroll
    for (int j = 0; j < 2; j++) acc[i][j] = f32x4{0.f, 0.f, 0.f, 0.f};

  for (int k0 = 0; k0 < E_; k0 += 32) {
    __syncthreads();
    for (int s = tid; s < 512; s += 256) {
      const int row = s >> 2, ch = s & 3;
      const int ko  = k0 + ch * 8;
      const size_t go = (size_t)(m0 + row) * E_ + ko;
      const int h = ko >> 6;
      const float g0 = gw[h][0], g1 = gw[h][1], g2 = gw[h][2];
      const bf16x8 v1 = *(const bf16x8*)(o1 + go);
      const bf16x8 v2 = *(const bf16x8*)(o2 + go);
      const bf16x8 v3 = *(const bf16x8*)(o3 + go);
      bf16x8 r;
      #pragma unroll
      for (int j = 0; j < 8; j++)
        r[j] = (short)f2bf(g0 * bf2f((u16)v1[j]) + g1 * bf2f((u16)v2[j]) + g2 * bf2f((u16)v3[j]));
      *(bf16x8*)&sA[s * 8] = r;
    }
    for (int s = tid; s < 256; s += 256) {
      const int row = s >> 2, ch = s & 3;
      GLD_LDS16(wob + (size_t)(n0 + row) * E_ + k0 + ch * 8, &sB[s * 8]);
    }
    __syncthreads();

    bf16x8 av[4], bv[2];
    #pragma unroll
    for (int mt = 0; mt < 4; mt++)
      av[mt] = *(const bf16x8*)&sA[((wm * 4 + mt) * 16 + fr) * 32 + fg * 8];
    #pragma unroll
    for (int nt = 0; nt < 2; nt++)
      bv[nt] = *(const bf16x8*)&sB[((wn * 2 + nt) * 16 + fr) * 32 + fg * 8];
    #pragma unroll
    for (int mt = 0; mt < 4; mt++)
      #pragma unroll
      for (int nt = 0; nt < 2; nt++)
        acc[mt][nt] = __builtin_amdgcn_mfma_f32_16x16x32_bf16(av[mt], bv[nt], acc[mt][nt], 0, 0, 0);
  }

  const int er = (lane >> 4) * 4;
  const int ec = lane & 15;
  #pragma unroll
  for (int mt = 0; mt < 4; mt++)
    #pragma unroll
    for (int nt = 0; nt < 2; nt++) {
      const int row = m0 + (wm * 4 + mt) * 16 + er;
      const int col = n0 + (wn * 2 + nt) * 16 + ec;
      #pragma unroll
      for (int r2 = 0; r2 < 4; r2++)
        out[(size_t)(row + r2) * E_ + col] = acc[mt][nt][r2];
    }
}

// ---------------------------------------------------------------------------
// cast_all: x split | wq/wk/wv/wvr -> wcat | wo | wj split | sc zero.
// ---------------------------------------------------------------------------
__global__ __launch_bounds__(256) void cast_all(
    const float* __restrict__ x, const float* __restrict__ wq,
    const float* __restrict__ wk, const float* __restrict__ wv,
    const float* __restrict__ wvr, const float* __restrict__ wo,
    const float* __restrict__ wj,
    u16* __restrict__ xb, u16* __restrict__ xlo, u16* __restrict__ wcat,
    u16* __restrict__ wob, u16* __restrict__ wjb, u16* __restrict__ wjlo,
    float* __restrict__ sc) {
  const int bid = blockIdx.x;
  if (bid < 4096) {
    const size_t i = ((size_t)bid * 256 + threadIdx.x) * 4;
    const float4 v = *(const float4*)(x + i);
    ushort4 oh, ol;
    oh.x = f2bf(v.x); ol.x = f2bf(v.x - bf2f(oh.x));
    oh.y = f2bf(v.y); ol.y = f2bf(v.y - bf2f(oh.y));
    oh.z = f2bf(v.z); ol.z = f2bf(v.z - bf2f(oh.z));
    oh.w = f2bf(v.w); ol.w = f2bf(v.w - bf2f(oh.w));
    *(ushort4*)(xb + i) = oh;
    *(ushort4*)(xlo + i) = ol;
  } else if (bid < 8192) {
    const int r = (bid - 4096) >> 10;
    const float* src = (r == 0) ? wq : (r == 1) ? wk : (r == 2) ? wv : wvr;
    const size_t i = ((size_t)((bid - 4096) & 1023) * 256 + threadIdx.x) * 4;
    const float4 v = *(const float4*)(src + i);
    ushort4 o;
    o.x = f2bf(v.x); o.y = f2bf(v.y); o.z = f2bf(v.z); o.w = f2bf(v.w);
    *(ushort4*)(wcat + (size_t)r * (1 << 20) + i) = o;
  } else if (bid < 9216) {
    const size_t i = ((size_t)(bid - 8192) * 256 + threadIdx.x) * 4;
    const float4 v = *(const float4*)(wo + i);
    ushort4 o;
    o.x = f2bf(v.x); o.y = f2bf(v.y); o.z = f2bf(v.z); o.w = f2bf(v.w);
    *(ushort4*)(wob + i) = o;
  } else if (bid < 10240) {
    const size_t i = ((size_t)(bid - 9216) * 256 + threadIdx.x) * 4;
    const float4 v = *(const float4*)(wj + i);
    ushort4 oh, ol;
    oh.x = f2bf(v.x); ol.x = f2bf(v.x - bf2f(oh.x));
    oh.y = f2bf(v.y); ol.y = f2bf(v.y - bf2f(oh.y));
    oh.z = f2bf(v.z); ol.z = f2bf(v.z - bf2f(oh.z));
    oh.w = f2bf(v.w); ol.w = f2bf(v.w - bf2f(oh.w));
    *(ushort4*)(wjb + i) = oh;
    *(ushort4*)(wjlo + i) = ol;
  } else {
    const float4 z = {0.f, 0.f, 0.f, 0.f};
    for (int i = threadIdx.x; i < 1024; i += 256) ((float4*)sc)[i] = z;
  }
}

// ---------------------------------------------------------------------------
// side_kernel: transpose_v (4096 blocks) + s2_direct (512 blocks).
// ---------------------------------------------------------------------------
__global__ __launch_bounds__(256) void side_kernel(
    const u16* __restrict__ qkvr, u16* __restrict__ vTb,
    const u16* __restrict__ xb, const float* __restrict__ wr, float* __restrict__ s2) {
  __shared__ __align__(16) char sbuf[8 * 4 * 33 * 4];   // max(tile 2112B, red 4224B)
  const int bid = blockIdx.x;
  if (bid < 4096) {
    // transpose_v: v view = qkvr cols [2048,3072), row stride 4096
    const int bh = bid & 63, r = bid >> 6;
    const int b = bh >> 4, h = bh & 15;
    const int d0 = (r & 1) * 32, t0 = (r >> 1) * 32;
    u16 (*tile)[33] = (u16(*)[33])sbuf;
    const int c = threadIdx.x & 31, r0 = threadIdx.x >> 5;
    const u16* v = qkvr + 2048;
    #pragma unroll
    for (int rr = 0; rr < 32; rr += 8) {
      const int t = t0 + rr + r0;
      tile[rr + r0][c] = v[((size_t)b * T_ + t) * 4096 + h * 64 + d0 + c];
    }
    __syncthreads();
    #pragma unroll
    for (int rr = 0; rr < 32; rr += 8) {
      const int d = d0 + rr + r0;
      const int t = t0 + c;
      vTb[((size_t)(bh * 128 + (t >> 3)) * 64 + d) * 8 + (t & 7)] = tile[c][rr + r0];
    }
  } else {
    const int sid = bid - 4096;
    const int t0 = (sid & 31) * 32, h = sid >> 5;
    const int tt = threadIdx.x & 31, eg = threadIdx.x >> 5;
    float acc[4] = {0.f, 0.f, 0.f, 0.f};
    const float* wp = wr + (size_t)h * E_ * T_ + t0 + tt;
    for (int ec = 0; ec < 8; ec++) {
      const int e0 = ec * 128 + eg * 16;
      bf16x8 xv[4][2];
      #pragma unroll
      for (int b = 0; b < 4; b++) {
        const u16* xp = xb + ((size_t)(b * T_) + t0 + tt) * E_ + e0;
        xv[b][0] = *(const bf16x8*)xp;
        xv[b][1] = *(const bf16x8*)(xp + 8);
      }
      #pragma unroll
      for (int e2 = 0; e2 < 16; e2++) {
        const float w = wp[(size_t)(e0 + e2) * T_];
        #pragma unroll
        for (int b = 0; b < 4; b++)
          acc[b] += bf2f((u16)xv[b][e2 >> 3][e2 & 7]) * w;
      }
    }
    float (*red)[4][33] = (float(*)[4][33])sbuf;
    #pragma unroll
    for (int b = 0; b < 4; b++) red[eg][b][tt] = acc[b];
    __syncthreads();
    if (threadIdx.x < 128) {
      const int b = threadIdx.x >> 5, t = threadIdx.x & 31;
      float s = 0.f;
      #pragma unroll
      for (int g = 0; g < 8; g++) s += red[g][b][t];
      s2[((size_t)b * H_ + h) * T_ + t0 + t] = s * 0.125f;
    }
  }
}

// ---------------------------------------------------------------------------
// scan_a3: branch2 prefix scan (64 blocks) + a3 softmax (4096 blocks), 1024 thr.
// ---------------------------------------------------------------------------
__global__ __launch_bounds__(1024) void scan_a3(
    const float* __restrict__ s2, const u16* __restrict__ rv, u16* __restrict__ out2,
    const float* __restrict__ sc, u16* __restrict__ a3p) {
  __shared__ float wbuf[1024];
  __shared__ float numtot[16][64];
  __shared__ float dentot[16];
  __shared__ float redm[16];
  const int bid = blockIdx.x;
  const int tid = threadIdx.x, lane = tid & 63, wv = tid >> 6;

  if (bid < 64) {
    const int h = bid & 15, b = bid >> 4;
    const float* srow = s2 + ((size_t)b * H_ + h) * T_;

    float m = srow[tid];
    #pragma unroll
    for (int mk = 32; mk > 0; mk >>= 1) m = fmaxf(m, __shfl_xor(m, mk, 64));
    if (lane == 0) redm[wv] = m;
    __syncthreads();
    m = redm[0];
    #pragma unroll
    for (int i2 = 1; i2 < 16; i2++) m = fmaxf(m, redm[i2]);

    wbuf[tid] = __expf(srow[tid] - m);
    __syncthreads();

    const u16* rvp = rv + (size_t)(b * T_) * 4096 + h * D_ + lane;
    const int j0 = wv * 64;
    float num = 0.f, den = 0.f;
    #pragma unroll 8
    for (int j2 = 0; j2 < 64; j2++) {
      const float w = wbuf[j0 + j2];
      den += w;
      num += w * bf2f(rvp[(size_t)(j0 + j2) * 4096]);
    }
    numtot[wv][lane] = num;
    if (lane == 0) dentot[wv] = den;
    __syncthreads();

    float num_off = 0.f, den_off = 0.f;
    for (int w2 = 0; w2 < wv; w2++) {
      num_off += numtot[w2][lane];
      den_off += dentot[w2];
    }

    u16* op = out2 + (size_t)b * T_ * E_ + h * D_ + lane;
    num = num_off; den = den_off;
    #pragma unroll 8
    for (int j2 = 0; j2 < 64; j2++) {
      const float w = wbuf[j0 + j2];
      num += w * bf2f(rvp[(size_t)(j0 + j2) * 4096]);
      den += w;
      op[(size_t)(j0 + j2) * E_] = f2bf(num / den);
    }
  } else {
    const int sid = bid - 64;
    const int i = sid & 1023, b = sid >> 10;
    const float* sr = sc + (size_t)b * T_;
    const float sci = sr[i] * 0.03125f;
    const int j = tid;
    const float xv = (j <= i) ? sci * (sr[j] * 0.03125f) : -3.0e38f;
    float m = xv;
    #pragma unroll
    for (int mk = 32; mk > 0; mk >>= 1) m = fmaxf(m, __shfl_xor(m, mk, 64));
    if (lane == 0) redm[wv] = m;
    __syncthreads();
    m = redm[0];
    #pragma unroll
    for (int i2 = 1; i2 < 16; i2++) m = fmaxf(m, redm[i2]);
    const float pv = (j <= i) ? __expf(xv - m) : 0.f;
    float s = pv;
    #pragma unroll
    for (int mk = 32; mk > 0; mk >>= 1) s += __shfl_xor(s, mk, 64);
    __syncthreads();
    if (lane == 0) redm[wv] = s;
    __syncthreads();
    s = 0.f;
    #pragma unroll
    for (int i2 = 0; i2 < 16; i2++) s += redm[i2];
    a3p[((size_t)b * T_ + i) * T_ + j] = f2bf(pv / s);
  }
}

// ---------------------------------------------------------------------------
extern "C" void kernel_launch(void* const* d_in, const int* in_sizes, int n_in,
                              void* d_out, int out_size, void* d_ws, size_t ws_size,
                              hipStream_t stream) {
  (void)in_sizes; (void)n_in; (void)out_size; (void)ws_size;
  const float* x    = (const float*)d_in[0];
  const float* wq   = (const float*)d_in[1];
  const float* wk   = (const float*)d_in[2];
  const float* wv   = (const float*)d_in[3];
  const float* wvr  = (const float*)d_in[4];
  const float* wr   = (const float*)d_in[5];
  const float* wj   = (const float*)d_in[6];
  const float* gate = (const float*)d_in[7];
  const float* wo   = (const float*)d_in[8];
  float* out = (float*)d_out;

  char* p = (char*)d_ws;
  auto alloc = [&](size_t bytes) -> char* {
    char* r = p; p += (bytes + 255) & ~(size_t)255; return r;
  };
  const size_t NTE = (size_t)B_ * T_ * E_;
  const size_t NW  = (size_t)E_ * E_;

  u16* xb    = (u16*)alloc(NTE * 2);
  u16* xlo   = (u16*)alloc(NTE * 2);
  u16* wcat  = (u16*)alloc(4 * NW * 2);
  u16* wjb   = (u16*)alloc(NW * 2);
  u16* wjlo  = (u16*)alloc(NW * 2);
  u16* wob   = (u16*)alloc(NW * 2);
  u16* qkvr  = (u16*)alloc(NTE * 4 * 2);     // (B*T, 4096): q|k|v|rv
  u16* vT    = (u16*)alloc(NTE * 2);         // blocked (bh, t8, d, 8)
  u16* echoT = (u16*)alloc(NTE * 2);         // (B, E, T) bf16
  u16* a3p   = (u16*)alloc(NTE * 2);
  float* sc  = (float*)alloc((size_t)B_ * T_ * 4);
  float* s2  = (float*)alloc((size_t)B_ * H_ * T_ * 4);
  u16* out1b = (u16*)alloc(NTE * 2);
  u16* out2b = (u16*)alloc(NTE * 2);
  u16* out3b = (u16*)alloc(NTE * 2);

  // 1. casts + sc zero
  cast_all<<<dim3(10241), 256, 0, stream>>>(x, wq, wk, wv, wvr, wo, wj,
                                            xb, xlo, wcat, wob, wjb, wjlo, sc);
  // 2. fused q|k|v|rv projection
  gemm_bt<2,2,4,4,true><<<dim3(32, 32, 1), 256, 0, stream>>>(
      xb, wcat, qkvr, 4096, E_, E_, E_, 4096, 0L, 0L, 0L, 1.f);
  // 3. echo split-GEMM (echoT + sc fused epilogue)
  gemm_echo<<<dim3(16, 32, 1), 256, 0, stream>>>(xb, xlo, wjb, wjlo, echoT, sc);
  // 4. transpose_v + s2_direct
  side_kernel<<<dim3(4608), 256, 0, stream>>>(qkvr, vT, xb, wr, s2);
  // 5. branch2 scan + a3 softmax
  scan_a3<<<dim3(4160), 1024, 0, stream>>>(s2, qkvr + 3072, out2b, sc, a3p);
  // 6. flash attention + out3 GEMM
  attn_out3<<<dim3(1024), 256, 0, stream>>>(qkvr, vT, out1b, a3p, echoT, out3b);
  // 7. gated combine fused into wo GEMM
  gemm_wo<<<dim3(16, 32), 256, 0, stream>>>(out1b, out2b, out3b, gate, wob, out);
}